// Round 1
// baseline (1245.070 us; speedup 1.0000x reference)
//
#include <hip/hip_runtime.h>
#include <cstddef>

#define N_NODES  50000
#define N_EDGES  600000
#define N_FEAT   128
#define N_GRAPHS 256
#define DIMM     95
#define N_OUTD   12
#define N_ITERS  10

// workspace layout (float offsets)
#define WS_BUF   0                       // [50000*128] h0 -> x1 (in place)
#define WS_STATS (N_NODES * N_FEAT)      // [256] colsum[128], colsumsq[128]
#define WS_SCALE (WS_STATS + 256)        // [256] scale[128], shift[128]
#define WS_XG    (WS_SCALE + 256)        // [256*128] pooled graph features

#define SR 132   // padded LDS row stride (128+4): breaks pow2 bank strides

// ---------------- init: buf = x (h0 accumulates on top), zero stats ----------
__global__ void k_init(const float* __restrict__ x, float* __restrict__ ws) {
    int tid = blockIdx.x * blockDim.x + threadIdx.x;
    const float4* xs = (const float4*)x;
    float4* bs = (float4*)(ws + WS_BUF);
    const int n4 = N_NODES * N_FEAT / 4;
    for (int i = tid; i < n4; i += gridDim.x * blockDim.x) bs[i] = xs[i];
    if (blockIdx.x == 0 && threadIdx.x < 256) ws[WS_STATS + threadIdx.x] = 0.f;
}

// ---------------- edge scatter-add: buf[dst] += x[src] ----------------------
__global__ void k_edges(const int* __restrict__ ei, const float* __restrict__ x,
                        float* __restrict__ buf) {
    int lane = threadIdx.x & 31;               // 32 lanes per edge, float4 each
    int e = blockIdx.x * 8 + (threadIdx.x >> 5);
    if (e >= N_EDGES) return;
    int src = ei[e];
    int dst = ei[N_EDGES + e];
    int c = lane * 4;
    float4 v = *(const float4*)(x + (size_t)src * N_FEAT + c);
    float* d = buf + (size_t)dst * N_FEAT + c;
    unsafeAtomicAdd(d + 0, v.x);
    unsafeAtomicAdd(d + 1, v.y);
    unsafeAtomicAdd(d + 2, v.z);
    unsafeAtomicAdd(d + 3, v.w);
}

// ------------- fused nn1: x1 = relu(relu(h0@W1a+b1a)@W1b+b1b), in place ------
__global__ __launch_bounds__(256, 2) void k_mlp(float* __restrict__ buf,
        const float* __restrict__ W1a, const float* __restrict__ b1a,
        const float* __restrict__ W1b, const float* __restrict__ b1b) {
    __shared__ float As[64 * SR];
    __shared__ float Ts[64 * SR];
    const int tid = threadIdx.x;
    const int fg = tid & 15;      // 16 feat groups x 8 feats
    const int rg = tid >> 4;      // 16 row groups  x 4 rows
    const int row0 = blockIdx.x * 64;

    // stage 64x128 input tile (coalesced float4)
    #pragma unroll
    for (int p = 0; p < 8; ++p) {
        int f4 = tid + p * 256;
        int r = f4 >> 5, c = (f4 & 31) * 4;
        float4 v = make_float4(0.f, 0.f, 0.f, 0.f);
        if (row0 + r < N_NODES) v = *(const float4*)(buf + (size_t)(row0 + r) * N_FEAT + c);
        *(float4*)(As + r * SR + c) = v;
    }
    __syncthreads();

    // ---- layer 1 ----
    float acc[4][8];
    #pragma unroll
    for (int i = 0; i < 4; ++i)
        #pragma unroll
        for (int j = 0; j < 8; ++j) acc[i][j] = 0.f;

    #pragma unroll 4
    for (int k = 0; k < N_FEAT; ++k) {
        const float4 w0 = *(const float4*)(W1a + k * N_FEAT + fg * 8);
        const float4 w1 = *(const float4*)(W1a + k * N_FEAT + fg * 8 + 4);
        #pragma unroll
        for (int i = 0; i < 4; ++i) {
            const float a = As[(rg * 4 + i) * SR + k];
            acc[i][0] += a * w0.x; acc[i][1] += a * w0.y;
            acc[i][2] += a * w0.z; acc[i][3] += a * w0.w;
            acc[i][4] += a * w1.x; acc[i][5] += a * w1.y;
            acc[i][6] += a * w1.z; acc[i][7] += a * w1.w;
        }
    }
    {
        const float4 ba0 = *(const float4*)(b1a + fg * 8);
        const float4 ba1 = *(const float4*)(b1a + fg * 8 + 4);
        #pragma unroll
        for (int i = 0; i < 4; ++i) {
            float4 u0, u1;
            u0.x = fmaxf(acc[i][0] + ba0.x, 0.f); u0.y = fmaxf(acc[i][1] + ba0.y, 0.f);
            u0.z = fmaxf(acc[i][2] + ba0.z, 0.f); u0.w = fmaxf(acc[i][3] + ba0.w, 0.f);
            u1.x = fmaxf(acc[i][4] + ba1.x, 0.f); u1.y = fmaxf(acc[i][5] + ba1.y, 0.f);
            u1.z = fmaxf(acc[i][6] + ba1.z, 0.f); u1.w = fmaxf(acc[i][7] + ba1.w, 0.f);
            *(float4*)(Ts + (rg * 4 + i) * SR + fg * 8)     = u0;
            *(float4*)(Ts + (rg * 4 + i) * SR + fg * 8 + 4) = u1;
        }
    }
    __syncthreads();

    // ---- layer 2 ----
    #pragma unroll
    for (int i = 0; i < 4; ++i)
        #pragma unroll
        for (int j = 0; j < 8; ++j) acc[i][j] = 0.f;

    #pragma unroll 4
    for (int k = 0; k < N_FEAT; ++k) {
        const float4 w0 = *(const float4*)(W1b + k * N_FEAT + fg * 8);
        const float4 w1 = *(const float4*)(W1b + k * N_FEAT + fg * 8 + 4);
        #pragma unroll
        for (int i = 0; i < 4; ++i) {
            const float a = Ts[(rg * 4 + i) * SR + k];
            acc[i][0] += a * w0.x; acc[i][1] += a * w0.y;
            acc[i][2] += a * w0.z; acc[i][3] += a * w0.w;
            acc[i][4] += a * w1.x; acc[i][5] += a * w1.y;
            acc[i][6] += a * w1.z; acc[i][7] += a * w1.w;
        }
    }
    {
        const float4 bb0 = *(const float4*)(b1b + fg * 8);
        const float4 bb1 = *(const float4*)(b1b + fg * 8 + 4);
        #pragma unroll
        for (int i = 0; i < 4; ++i) {
            int r = row0 + rg * 4 + i;
            if (r < N_NODES) {
                float4 u0, u1;
                u0.x = fmaxf(acc[i][0] + bb0.x, 0.f); u0.y = fmaxf(acc[i][1] + bb0.y, 0.f);
                u0.z = fmaxf(acc[i][2] + bb0.z, 0.f); u0.w = fmaxf(acc[i][3] + bb0.w, 0.f);
                u1.x = fmaxf(acc[i][4] + bb1.x, 0.f); u1.y = fmaxf(acc[i][5] + bb1.y, 0.f);
                u1.z = fmaxf(acc[i][6] + bb1.z, 0.f); u1.w = fmaxf(acc[i][7] + bb1.w, 0.f);
                *(float4*)(buf + (size_t)r * N_FEAT + fg * 8)     = u0;
                *(float4*)(buf + (size_t)r * N_FEAT + fg * 8 + 4) = u1;
            }
        }
    }
}

// --------- column sums / sums-of-squares of x1 (for BN batch stats) ---------
__global__ void k_stats(const float* __restrict__ buf, float* __restrict__ stats) {
    __shared__ float S[8][128];
    __shared__ float Q[8][128];
    const int tid = threadIdx.x;
    const int cg = tid & 31;   // float4 column group
    const int rg = tid >> 5;   // 8 parallel row streams
    float4 s = make_float4(0.f, 0.f, 0.f, 0.f);
    float4 q = make_float4(0.f, 0.f, 0.f, 0.f);
    for (int r = blockIdx.x * 8 + rg; r < N_NODES; r += gridDim.x * 8) {
        float4 v = *(const float4*)(buf + (size_t)r * N_FEAT + cg * 4);
        s.x += v.x; s.y += v.y; s.z += v.z; s.w += v.w;
        q.x += v.x * v.x; q.y += v.y * v.y; q.z += v.z * v.z; q.w += v.w * v.w;
    }
    S[rg][cg * 4 + 0] = s.x; S[rg][cg * 4 + 1] = s.y;
    S[rg][cg * 4 + 2] = s.z; S[rg][cg * 4 + 3] = s.w;
    Q[rg][cg * 4 + 0] = q.x; Q[rg][cg * 4 + 1] = q.y;
    Q[rg][cg * 4 + 2] = q.z; Q[rg][cg * 4 + 3] = q.w;
    __syncthreads();
    if (tid < 128) {
        float t = 0.f;
        #pragma unroll
        for (int g = 0; g < 8; ++g) t += S[g][tid];
        unsafeAtomicAdd(stats + tid, t);
    } else {
        int c = tid - 128;
        float t = 0.f;
        #pragma unroll
        for (int g = 0; g < 8; ++g) t += Q[g][c];
        unsafeAtomicAdd(stats + 128 + c, t);
    }
}

// --------- finalize BN: scale = gamma*rsqrt(var+eps), shift = beta-mean*scale
__global__ void k_finalize(const float* __restrict__ gamma, const float* __restrict__ beta,
                           float* __restrict__ ws) {
    int c = threadIdx.x;
    float mean = ws[WS_STATS + c] * (1.f / N_NODES);
    float var  = fmaxf(ws[WS_STATS + 128 + c] * (1.f / N_NODES) - mean * mean, 0.f);
    float sc = gamma[c] * rsqrtf(var + 1e-5f);
    ws[WS_SCALE + c] = sc;
    ws[WS_SCALE + 128 + c] = beta[c] - mean * sc;
}

__device__ __forceinline__ int lbound(const int* __restrict__ a, int n, int v) {
    int lo = 0, hi = n;
    while (lo < hi) { int m = (lo + hi) >> 1; if (a[m] < v) lo = m + 1; else hi = m; }
    return lo;
}

// --------- per-graph mean pool with BN applied on the fly -------------------
__global__ void k_pool(const float* __restrict__ buf, const int* __restrict__ batch,
                       float* __restrict__ ws) {
    __shared__ float S[8][128];
    __shared__ int range[2];
    const int g = blockIdx.x, tid = threadIdx.x;
    if (tid == 0) {
        range[0] = lbound(batch, N_NODES, g);
        range[1] = lbound(batch, N_NODES, g + 1);
    }
    __syncthreads();
    const int lo = range[0], hi = range[1];
    const int cg = tid & 31, rg = tid >> 5;
    float4 s = make_float4(0.f, 0.f, 0.f, 0.f);
    for (int r = lo + rg; r < hi; r += 8) {
        float4 v = *(const float4*)(buf + (size_t)r * N_FEAT + cg * 4);
        s.x += v.x; s.y += v.y; s.z += v.z; s.w += v.w;
    }
    S[rg][cg * 4 + 0] = s.x; S[rg][cg * 4 + 1] = s.y;
    S[rg][cg * 4 + 2] = s.z; S[rg][cg * 4 + 3] = s.w;
    __syncthreads();
    if (tid < 128) {
        float t = 0.f;
        #pragma unroll
        for (int g8 = 0; g8 < 8; ++g8) t += S[g8][tid];
        int cnt = hi - lo;
        float sc = ws[WS_SCALE + tid], sh = ws[WS_SCALE + 128 + tid];
        ws[WS_XG + g * N_FEAT + tid] = (cnt > 0) ? (sc * t / (float)cnt + sh) : 0.f;
    }
}

// --------- 10-iter gated recurrence + output MLP, block per graph -----------
// p = cat@Wl1+bl1, q = cat@Wl2+bl2, h = [tanh(q), sigmoid(p)]; cat=[xg,h].
// xg half of both GEMVs is loop-invariant -> hoisted (px).
__global__ __launch_bounds__(256) void k_recur(const float* __restrict__ ws,
        const float* __restrict__ Wl1, const float* __restrict__ bl1,
        const float* __restrict__ Wl2, const float* __restrict__ bl2,
        const float* __restrict__ Wm1, const float* __restrict__ bm1,
        const float* __restrict__ Wm2, const float* __restrict__ bm2,
        float* __restrict__ out) {
    __shared__ float W1h[128 * 64];   // Wl1 rows 128..255 (h part)
    __shared__ float W2h[128 * 64];
    __shared__ float xg_s[128];
    __shared__ float h_s[128];
    __shared__ float px[2][64];
    __shared__ float pq[2][2][64];
    __shared__ float m_s[DIMM];
    const int g = blockIdx.x, tid = threadIdx.x;

    for (int i = tid; i < 128 * 64; i += 256) {
        W1h[i] = Wl1[128 * 64 + i];
        W2h[i] = Wl2[128 * 64 + i];
    }
    if (tid < 128) {
        float v = ws[WS_XG + g * N_FEAT + tid];
        xg_s[tid] = v;
        h_s[tid] = v;   // h0 = xg
    }
    __syncthreads();

    const int sel  = tid >> 7;        // 0: p (Wl1), 1: q (Wl2)
    const int part = (tid >> 6) & 1;  // k-half
    const int j    = tid & 63;

    // hoisted xg contribution (weights rows 0..127, straight from global/L2)
    {
        const float* Wg = sel ? Wl2 : Wl1;
        float a = 0.f;
        const int k0 = part * 64;
        #pragma unroll 4
        for (int k = 0; k < 64; ++k) a += xg_s[k0 + k] * Wg[(k0 + k) * 64 + j];
        pq[sel][part][j] = a;
    }
    __syncthreads();
    if (part == 0) {
        const float* bias = sel ? bl2 : bl1;
        px[sel][j] = pq[sel][0][j] + pq[sel][1][j] + bias[j];
    }
    __syncthreads();

    const float* Wh = sel ? W2h : W1h;
    for (int it = 0; it < N_ITERS; ++it) {
        float a = 0.f;
        const int k0 = part * 64;
        #pragma unroll
        for (int k = 0; k < 64; k += 4) {
            const float4 h4 = *(const float4*)(h_s + k0 + k);
            a += h4.x * Wh[(k0 + k + 0) * 64 + j];
            a += h4.y * Wh[(k0 + k + 1) * 64 + j];
            a += h4.z * Wh[(k0 + k + 2) * 64 + j];
            a += h4.w * Wh[(k0 + k + 3) * 64 + j];
        }
        pq[sel][part][j] = a;
        __syncthreads();
        if (part == 0) {
            float tot = pq[sel][0][j] + pq[sel][1][j] + px[sel][j];
            if (sel == 0) h_s[64 + j] = 1.f / (1.f + expf(-tot)); // sigmoid(p)
            else          h_s[j] = tanhf(tot);                    // tanh(q)
        }
        __syncthreads();
    }

    // output MLP: relu(h@Wm1+bm1)@Wm2+bm2
    if (tid < DIMM) {
        float a = bm1[tid];
        #pragma unroll 4
        for (int k = 0; k < 128; ++k) a += h_s[k] * Wm1[k * DIMM + tid];
        m_s[tid] = fmaxf(a, 0.f);
    }
    __syncthreads();
    if (tid < N_OUTD) {
        float a = bm2[tid];
        for (int k = 0; k < DIMM; ++k) a += m_s[k] * Wm2[k * N_OUTD + tid];
        out[g * N_OUTD + tid] = a;
    }
}

extern "C" void kernel_launch(void* const* d_in, const int* in_sizes, int n_in,
                              void* d_out, int out_size, void* d_ws, size_t ws_size,
                              hipStream_t stream) {
    const float* x     = (const float*)d_in[0];
    const int*   ei    = (const int*)d_in[1];
    const int*   batch = (const int*)d_in[2];
    const float* W1a = (const float*)d_in[3];
    const float* b1a = (const float*)d_in[4];
    const float* W1b = (const float*)d_in[5];
    const float* b1b = (const float*)d_in[6];
    const float* gamma = (const float*)d_in[7];
    const float* beta  = (const float*)d_in[8];
    const float* Wl1 = (const float*)d_in[9];
    const float* bl1 = (const float*)d_in[10];
    const float* Wl2 = (const float*)d_in[11];
    const float* bl2 = (const float*)d_in[12];
    const float* Wm1 = (const float*)d_in[13];
    const float* bm1 = (const float*)d_in[14];
    const float* Wm2 = (const float*)d_in[15];
    const float* bm2 = (const float*)d_in[16];
    float* out = (float*)d_out;
    float* ws  = (float*)d_ws;

    k_init<<<1024, 256, 0, stream>>>(x, ws);
    k_edges<<<N_EDGES / 8, 256, 0, stream>>>(ei, x, ws + WS_BUF);
    k_mlp<<<(N_NODES + 63) / 64, 256, 0, stream>>>(ws + WS_BUF, W1a, b1a, W1b, b1b);
    k_stats<<<512, 256, 0, stream>>>(ws + WS_BUF, ws + WS_STATS);
    k_finalize<<<1, 128, 0, stream>>>(gamma, beta, ws);
    k_pool<<<N_GRAPHS, 256, 0, stream>>>(ws + WS_BUF, batch, ws);
    k_recur<<<N_GRAPHS, 256, 0, stream>>>(ws, Wl1, bl1, Wl2, bl2, Wm1, bm1, Wm2, bm2, out);
}

// Round 2
// 762.380 us; speedup vs baseline: 1.6331x; 1.6331x over previous
//
#include <hip/hip_runtime.h>
#include <cstddef>

#define N_NODES  50000
#define N_EDGES  600000
#define N_FEAT   128
#define N_GRAPHS 256
#define DIMM     95
#define N_OUTD   12
#define N_ITERS  10

// workspace layout (float offsets)
#define WS_BUF   0                       // [50000*128] h0 -> x1 (in place)
#define WS_STATS (N_NODES * N_FEAT)      // [256] colsum[128], colsumsq[128]
#define WS_SCALE (WS_STATS + 256)        // [256] scale[128], shift[128]
#define WS_XG    (WS_SCALE + 256)        // [256*128] pooled graph features

#define SR 132   // padded LDS row stride (128+4)

// rows of the aggregation owned per block (LDS accumulator)
#define ROWS_PB 120
#define AGG_BLOCKS ((N_NODES + ROWS_PB - 1) / ROWS_PB)   // 417

// ---------------- owner-computes edge aggregation ---------------------------
// Each block owns ROWS_PB dst rows in an LDS f32 accumulator. It scans the
// whole dst array (L2-resident), ballots for matches, gathers x[src] for the
// ~0.24% matching edges, accumulates via LDS atomics (no global atomics),
// then writes buf = x + agg with plain coalesced stores.
__global__ __launch_bounds__(256) void k_agg(const int* __restrict__ ei,
                                             const float* __restrict__ x,
                                             float* __restrict__ ws) {
    __shared__ float acc[ROWS_PB * N_FEAT];   // 61440 B -> 2 blocks/CU
    const int tid  = threadIdx.x;
    const int lane = tid & 63;
    const int wv   = tid >> 6;                 // 4 waves
    const int row0 = blockIdx.x * ROWS_PB;
    const int nrows = min(ROWS_PB, N_NODES - row0);

    // zero accumulator
    #pragma unroll
    for (int i = tid; i < ROWS_PB * N_FEAT; i += 256) acc[i] = 0.f;
    // zero BN stats (any single block; kernel boundary orders vs k_stats)
    if (blockIdx.x == 0) ws[WS_STATS + tid] = 0.f;
    __syncthreads();

    const int* __restrict__ srcp = ei;
    const int* __restrict__ dstp = ei + N_EDGES;

    // each wave scans a quarter of the edge list
    const int wbase = wv * (N_EDGES / 4);
    const int wend  = wbase + (N_EDGES / 4);

    for (int e0 = wbase; e0 < wend; e0 += 256) {
        int dv[4];
        #pragma unroll
        for (int u = 0; u < 4; ++u) {
            int e = e0 + u * 64 + lane;
            dv[u] = (e < wend) ? dstp[e] : 0x7fffffff;
        }
        #pragma unroll
        for (int u = 0; u < 4; ++u) {
            int relv = dv[u] - row0;
            bool m = (unsigned)relv < (unsigned)nrows;
            unsigned long long mask = __ballot(m);
            while (mask) {
                int eids[4], rls[4];
                int n = 0;
                #pragma unroll
                for (int t = 0; t < 4; ++t) {
                    if (mask) {
                        int b = __ffsll(mask) - 1;
                        mask &= mask - 1;
                        eids[n] = e0 + u * 64 + b;
                        rls[n]  = __shfl(relv, b);
                        ++n;
                    }
                }
                int sids[4];
                for (int t = 0; t < n; ++t) sids[t] = srcp[eids[t]];
                float v0[4], v1[4];
                for (int t = 0; t < n; ++t) {
                    const float* xr = x + (size_t)sids[t] * N_FEAT;
                    v0[t] = xr[lane];
                    v1[t] = xr[64 + lane];
                }
                for (int t = 0; t < n; ++t) {
                    atomicAdd(&acc[rls[t] * N_FEAT + lane],      v0[t]);  // ds_add_f32
                    atomicAdd(&acc[rls[t] * N_FEAT + 64 + lane], v1[t]);
                }
            }
        }
    }
    __syncthreads();

    // buf = x + agg (coalesced float4)
    float* __restrict__ buf = ws + WS_BUF;
    for (int i = tid; i < nrows * 32; i += 256) {
        int rl = i >> 5, c4 = (i & 31) * 4;
        int r = row0 + rl;
        float4 a = *(float4*)(acc + rl * N_FEAT + c4);
        float4 xv = *(const float4*)(x + (size_t)r * N_FEAT + c4);
        a.x += xv.x; a.y += xv.y; a.z += xv.z; a.w += xv.w;
        *(float4*)(buf + (size_t)r * N_FEAT + c4) = a;
    }
}

// ------------- fused nn1: x1 = relu(relu(h0@W1a+b1a)@W1b+b1b), in place ------
__global__ __launch_bounds__(256, 2) void k_mlp(float* __restrict__ buf,
        const float* __restrict__ W1a, const float* __restrict__ b1a,
        const float* __restrict__ W1b, const float* __restrict__ b1b) {
    __shared__ float As[64 * SR];
    __shared__ float Ts[64 * SR];
    const int tid = threadIdx.x;
    const int fg = tid & 15;      // 16 feat groups x 8 feats
    const int rg = tid >> 4;      // 16 row groups  x 4 rows
    const int row0 = blockIdx.x * 64;

    // stage 64x128 input tile (coalesced float4)
    #pragma unroll
    for (int p = 0; p < 8; ++p) {
        int f4 = tid + p * 256;
        int r = f4 >> 5, c = (f4 & 31) * 4;
        float4 v = make_float4(0.f, 0.f, 0.f, 0.f);
        if (row0 + r < N_NODES) v = *(const float4*)(buf + (size_t)(row0 + r) * N_FEAT + c);
        *(float4*)(As + r * SR + c) = v;
    }
    __syncthreads();

    // ---- layer 1 ----
    float acc[4][8];
    #pragma unroll
    for (int i = 0; i < 4; ++i)
        #pragma unroll
        for (int j = 0; j < 8; ++j) acc[i][j] = 0.f;

    #pragma unroll 4
    for (int k = 0; k < N_FEAT; ++k) {
        const float4 w0 = *(const float4*)(W1a + k * N_FEAT + fg * 8);
        const float4 w1 = *(const float4*)(W1a + k * N_FEAT + fg * 8 + 4);
        #pragma unroll
        for (int i = 0; i < 4; ++i) {
            const float a = As[(rg * 4 + i) * SR + k];
            acc[i][0] += a * w0.x; acc[i][1] += a * w0.y;
            acc[i][2] += a * w0.z; acc[i][3] += a * w0.w;
            acc[i][4] += a * w1.x; acc[i][5] += a * w1.y;
            acc[i][6] += a * w1.z; acc[i][7] += a * w1.w;
        }
    }
    {
        const float4 ba0 = *(const float4*)(b1a + fg * 8);
        const float4 ba1 = *(const float4*)(b1a + fg * 8 + 4);
        #pragma unroll
        for (int i = 0; i < 4; ++i) {
            float4 u0, u1;
            u0.x = fmaxf(acc[i][0] + ba0.x, 0.f); u0.y = fmaxf(acc[i][1] + ba0.y, 0.f);
            u0.z = fmaxf(acc[i][2] + ba0.z, 0.f); u0.w = fmaxf(acc[i][3] + ba0.w, 0.f);
            u1.x = fmaxf(acc[i][4] + ba1.x, 0.f); u1.y = fmaxf(acc[i][5] + ba1.y, 0.f);
            u1.z = fmaxf(acc[i][6] + ba1.z, 0.f); u1.w = fmaxf(acc[i][7] + ba1.w, 0.f);
            *(float4*)(Ts + (rg * 4 + i) * SR + fg * 8)     = u0;
            *(float4*)(Ts + (rg * 4 + i) * SR + fg * 8 + 4) = u1;
        }
    }
    __syncthreads();

    // ---- layer 2 ----
    #pragma unroll
    for (int i = 0; i < 4; ++i)
        #pragma unroll
        for (int j = 0; j < 8; ++j) acc[i][j] = 0.f;

    #pragma unroll 4
    for (int k = 0; k < N_FEAT; ++k) {
        const float4 w0 = *(const float4*)(W1b + k * N_FEAT + fg * 8);
        const float4 w1 = *(const float4*)(W1b + k * N_FEAT + fg * 8 + 4);
        #pragma unroll
        for (int i = 0; i < 4; ++i) {
            const float a = Ts[(rg * 4 + i) * SR + k];
            acc[i][0] += a * w0.x; acc[i][1] += a * w0.y;
            acc[i][2] += a * w0.z; acc[i][3] += a * w0.w;
            acc[i][4] += a * w1.x; acc[i][5] += a * w1.y;
            acc[i][6] += a * w1.z; acc[i][7] += a * w1.w;
        }
    }
    {
        const float4 bb0 = *(const float4*)(b1b + fg * 8);
        const float4 bb1 = *(const float4*)(b1b + fg * 8 + 4);
        #pragma unroll
        for (int i = 0; i < 4; ++i) {
            int r = row0 + rg * 4 + i;
            if (r < N_NODES) {
                float4 u0, u1;
                u0.x = fmaxf(acc[i][0] + bb0.x, 0.f); u0.y = fmaxf(acc[i][1] + bb0.y, 0.f);
                u0.z = fmaxf(acc[i][2] + bb0.z, 0.f); u0.w = fmaxf(acc[i][3] + bb0.w, 0.f);
                u1.x = fmaxf(acc[i][4] + bb1.x, 0.f); u1.y = fmaxf(acc[i][5] + bb1.y, 0.f);
                u1.z = fmaxf(acc[i][6] + bb1.z, 0.f); u1.w = fmaxf(acc[i][7] + bb1.w, 0.f);
                *(float4*)(buf + (size_t)r * N_FEAT + fg * 8)     = u0;
                *(float4*)(buf + (size_t)r * N_FEAT + fg * 8 + 4) = u1;
            }
        }
    }
}

// --------- column sums / sums-of-squares of x1 (for BN batch stats) ---------
__global__ void k_stats(const float* __restrict__ buf, float* __restrict__ stats) {
    __shared__ float S[8][128];
    __shared__ float Q[8][128];
    const int tid = threadIdx.x;
    const int cg = tid & 31;   // float4 column group
    const int rg = tid >> 5;   // 8 parallel row streams
    float4 s = make_float4(0.f, 0.f, 0.f, 0.f);
    float4 q = make_float4(0.f, 0.f, 0.f, 0.f);
    for (int r = blockIdx.x * 8 + rg; r < N_NODES; r += gridDim.x * 8) {
        float4 v = *(const float4*)(buf + (size_t)r * N_FEAT + cg * 4);
        s.x += v.x; s.y += v.y; s.z += v.z; s.w += v.w;
        q.x += v.x * v.x; q.y += v.y * v.y; q.z += v.z * v.z; q.w += v.w * v.w;
    }
    S[rg][cg * 4 + 0] = s.x; S[rg][cg * 4 + 1] = s.y;
    S[rg][cg * 4 + 2] = s.z; S[rg][cg * 4 + 3] = s.w;
    Q[rg][cg * 4 + 0] = q.x; Q[rg][cg * 4 + 1] = q.y;
    Q[rg][cg * 4 + 2] = q.z; Q[rg][cg * 4 + 3] = q.w;
    __syncthreads();
    if (tid < 128) {
        float t = 0.f;
        #pragma unroll
        for (int g = 0; g < 8; ++g) t += S[g][tid];
        unsafeAtomicAdd(stats + tid, t);
    } else {
        int c = tid - 128;
        float t = 0.f;
        #pragma unroll
        for (int g = 0; g < 8; ++g) t += Q[g][c];
        unsafeAtomicAdd(stats + 128 + c, t);
    }
}

// --------- finalize BN: scale = gamma*rsqrt(var+eps), shift = beta-mean*scale
__global__ void k_finalize(const float* __restrict__ gamma, const float* __restrict__ beta,
                           float* __restrict__ ws) {
    int c = threadIdx.x;
    float mean = ws[WS_STATS + c] * (1.f / N_NODES);
    float var  = fmaxf(ws[WS_STATS + 128 + c] * (1.f / N_NODES) - mean * mean, 0.f);
    float sc = gamma[c] * rsqrtf(var + 1e-5f);
    ws[WS_SCALE + c] = sc;
    ws[WS_SCALE + 128 + c] = beta[c] - mean * sc;
}

__device__ __forceinline__ int lbound(const int* __restrict__ a, int n, int v) {
    int lo = 0, hi = n;
    while (lo < hi) { int m = (lo + hi) >> 1; if (a[m] < v) lo = m + 1; else hi = m; }
    return lo;
}

// --------- per-graph mean pool with BN applied on the fly -------------------
__global__ void k_pool(const float* __restrict__ buf, const int* __restrict__ batch,
                       float* __restrict__ ws) {
    __shared__ float S[8][128];
    __shared__ int range[2];
    const int g = blockIdx.x, tid = threadIdx.x;
    if (tid == 0) {
        range[0] = lbound(batch, N_NODES, g);
        range[1] = lbound(batch, N_NODES, g + 1);
    }
    __syncthreads();
    const int lo = range[0], hi = range[1];
    const int cg = tid & 31, rg = tid >> 5;
    float4 s = make_float4(0.f, 0.f, 0.f, 0.f);
    for (int r = lo + rg; r < hi; r += 8) {
        float4 v = *(const float4*)(buf + (size_t)r * N_FEAT + cg * 4);
        s.x += v.x; s.y += v.y; s.z += v.z; s.w += v.w;
    }
    S[rg][cg * 4 + 0] = s.x; S[rg][cg * 4 + 1] = s.y;
    S[rg][cg * 4 + 2] = s.z; S[rg][cg * 4 + 3] = s.w;
    __syncthreads();
    if (tid < 128) {
        float t = 0.f;
        #pragma unroll
        for (int g8 = 0; g8 < 8; ++g8) t += S[g8][tid];
        int cnt = hi - lo;
        float sc = ws[WS_SCALE + tid], sh = ws[WS_SCALE + 128 + tid];
        ws[WS_XG + g * N_FEAT + tid] = (cnt > 0) ? (sc * t / (float)cnt + sh) : 0.f;
    }
}

// --------- 10-iter gated recurrence + output MLP, block per graph -----------
__global__ __launch_bounds__(256) void k_recur(const float* __restrict__ ws,
        const float* __restrict__ Wl1, const float* __restrict__ bl1,
        const float* __restrict__ Wl2, const float* __restrict__ bl2,
        const float* __restrict__ Wm1, const float* __restrict__ bm1,
        const float* __restrict__ Wm2, const float* __restrict__ bm2,
        float* __restrict__ out) {
    __shared__ float W1h[128 * 64];   // Wl1 rows 128..255 (h part)
    __shared__ float W2h[128 * 64];
    __shared__ float xg_s[128];
    __shared__ float h_s[128];
    __shared__ float px[2][64];
    __shared__ float pq[2][2][64];
    __shared__ float m_s[DIMM];
    const int g = blockIdx.x, tid = threadIdx.x;

    for (int i = tid; i < 128 * 64; i += 256) {
        W1h[i] = Wl1[128 * 64 + i];
        W2h[i] = Wl2[128 * 64 + i];
    }
    if (tid < 128) {
        float v = ws[WS_XG + g * N_FEAT + tid];
        xg_s[tid] = v;
        h_s[tid] = v;   // h0 = xg
    }
    __syncthreads();

    const int sel  = tid >> 7;        // 0: p (Wl1), 1: q (Wl2)
    const int part = (tid >> 6) & 1;  // k-half
    const int j    = tid & 63;

    // hoisted xg contribution (weights rows 0..127, straight from global/L2)
    {
        const float* Wg = sel ? Wl2 : Wl1;
        float a = 0.f;
        const int k0 = part * 64;
        #pragma unroll 4
        for (int k = 0; k < 64; ++k) a += xg_s[k0 + k] * Wg[(k0 + k) * 64 + j];
        pq[sel][part][j] = a;
    }
    __syncthreads();
    if (part == 0) {
        const float* bias = sel ? bl2 : bl1;
        px[sel][j] = pq[sel][0][j] + pq[sel][1][j] + bias[j];
    }
    __syncthreads();

    const float* Wh = sel ? W2h : W1h;
    for (int it = 0; it < N_ITERS; ++it) {
        float a = 0.f;
        const int k0 = part * 64;
        #pragma unroll
        for (int k = 0; k < 64; k += 4) {
            const float4 h4 = *(const float4*)(h_s + k0 + k);
            a += h4.x * Wh[(k0 + k + 0) * 64 + j];
            a += h4.y * Wh[(k0 + k + 1) * 64 + j];
            a += h4.z * Wh[(k0 + k + 2) * 64 + j];
            a += h4.w * Wh[(k0 + k + 3) * 64 + j];
        }
        pq[sel][part][j] = a;
        __syncthreads();
        if (part == 0) {
            float tot = pq[sel][0][j] + pq[sel][1][j] + px[sel][j];
            if (sel == 0) h_s[64 + j] = 1.f / (1.f + expf(-tot)); // sigmoid(p)
            else          h_s[j] = tanhf(tot);                    // tanh(q)
        }
        __syncthreads();
    }

    // output MLP: relu(h@Wm1+bm1)@Wm2+bm2
    if (tid < DIMM) {
        float a = bm1[tid];
        #pragma unroll 4
        for (int k = 0; k < 128; ++k) a += h_s[k] * Wm1[k * DIMM + tid];
        m_s[tid] = fmaxf(a, 0.f);
    }
    __syncthreads();
    if (tid < N_OUTD) {
        float a = bm2[tid];
        for (int k = 0; k < DIMM; ++k) a += m_s[k] * Wm2[k * N_OUTD + tid];
        out[g * N_OUTD + tid] = a;
    }
}

extern "C" void kernel_launch(void* const* d_in, const int* in_sizes, int n_in,
                              void* d_out, int out_size, void* d_ws, size_t ws_size,
                              hipStream_t stream) {
    const float* x     = (const float*)d_in[0];
    const int*   ei    = (const int*)d_in[1];
    const int*   batch = (const int*)d_in[2];
    const float* W1a = (const float*)d_in[3];
    const float* b1a = (const float*)d_in[4];
    const float* W1b = (const float*)d_in[5];
    const float* b1b = (const float*)d_in[6];
    const float* gamma = (const float*)d_in[7];
    const float* beta  = (const float*)d_in[8];
    const float* Wl1 = (const float*)d_in[9];
    const float* bl1 = (const float*)d_in[10];
    const float* Wl2 = (const float*)d_in[11];
    const float* bl2 = (const float*)d_in[12];
    const float* Wm1 = (const float*)d_in[13];
    const float* bm1 = (const float*)d_in[14];
    const float* Wm2 = (const float*)d_in[15];
    const float* bm2 = (const float*)d_in[16];
    float* out = (float*)d_out;
    float* ws  = (float*)d_ws;

    k_agg<<<AGG_BLOCKS, 256, 0, stream>>>(ei, x, ws);
    k_mlp<<<(N_NODES + 63) / 64, 256, 0, stream>>>(ws + WS_BUF, W1a, b1a, W1b, b1b);
    k_stats<<<512, 256, 0, stream>>>(ws + WS_BUF, ws + WS_STATS);
    k_finalize<<<1, 128, 0, stream>>>(gamma, beta, ws);
    k_pool<<<N_GRAPHS, 256, 0, stream>>>(ws + WS_BUF, batch, ws);
    k_recur<<<N_GRAPHS, 256, 0, stream>>>(ws, Wl1, bl1, Wl2, bl2, Wm1, bm1, Wm2, bm2, out);
}

// Round 3
// 336.273 us; speedup vs baseline: 3.7026x; 2.2671x over previous
//
#include <hip/hip_runtime.h>
#include <cstddef>

#define N_NODES  50000
#define N_EDGES  600000
#define N_FEAT   128
#define N_GRAPHS 256
#define DIMM     95
#define N_OUTD   12
#define N_ITERS  10

#define N_CHUNKS 196          // ceil(50000/256)

// workspace layout (float-element offsets; int arrays reinterpret the region)
#define WS_BUF   0                        // [50000*128] h0 -> x1 (in place)
#define WS_STATS (N_NODES * N_FEAT)       // [256] colsum[128], colsumsq[128]
#define WS_SCALE (WS_STATS + 256)         // [256] scale[128], shift[128]
#define WS_XG    (WS_SCALE + 256)         // [256*128]
#define WS_CNT   (WS_XG + N_GRAPHS * N_FEAT)   // int[50000] per-node degree
#define WS_OFF   (WS_CNT + N_NODES)            // int[50001] CSR offsets (pad 50004)
#define WS_CUR   (WS_OFF + N_NODES + 4)        // int[50000] scatter cursors
#define WS_CHS   (WS_CUR + N_NODES)            // int[256] chunk sums
#define WS_SORT  (WS_CHS + 256)                // int[600000] src sorted by dst

#define SR 132   // padded LDS row stride (128+4)

// ---- zero degree counters + BN stats ---------------------------------------
__global__ void k_zero(float* __restrict__ ws) {
    int i = blockIdx.x * 256 + threadIdx.x;
    int* cnt = (int*)ws + WS_CNT;
    if (i < N_NODES) cnt[i] = 0;
    if (blockIdx.x == 0) ws[WS_STATS + threadIdx.x] = 0.f;
}

// ---- degree histogram ------------------------------------------------------
__global__ void k_hist(const int* __restrict__ ei, float* __restrict__ ws) {
    int e = blockIdx.x * 256 + threadIdx.x;
    int* cnt = (int*)ws + WS_CNT;
    if (e < N_EDGES) atomicAdd(&cnt[ei[N_EDGES + e]], 1);
}

// ---- per-chunk sums (chunk = 256 nodes) ------------------------------------
__global__ void k_chunk(float* __restrict__ ws) {
    __shared__ int red[4];
    const int tid = threadIdx.x;
    int* cnt = (int*)ws + WS_CNT;
    int i = blockIdx.x * 256 + tid;
    int v = (i < N_NODES) ? cnt[i] : 0;
    #pragma unroll
    for (int d = 32; d; d >>= 1) v += __shfl_down(v, d);
    if ((tid & 63) == 0) red[tid >> 6] = v;
    __syncthreads();
    if (tid == 0) ((int*)ws + WS_CHS)[blockIdx.x] = red[0] + red[1] + red[2] + red[3];
}

// ---- exclusive scan of the (<=256) chunk sums, single block ----------------
__global__ void k_scan0(float* __restrict__ ws) {
    __shared__ int s[256];
    const int tid = threadIdx.x;
    int* chs = (int*)ws + WS_CHS;
    int v = (tid < N_CHUNKS) ? chs[tid] : 0;
    s[tid] = v;
    __syncthreads();
    #pragma unroll
    for (int d = 1; d < 256; d <<= 1) {
        int t = (tid >= d) ? s[tid - d] : 0;
        __syncthreads();
        s[tid] += t;
        __syncthreads();
    }
    if (tid < N_CHUNKS) chs[tid] = s[tid] - v;            // exclusive
    if (tid == 0) ((int*)ws + WS_OFF)[N_NODES] = N_EDGES; // sentinel
}

// ---- per-chunk exclusive scan -> CSR offsets + cursor copy -----------------
__global__ void k_scan1(float* __restrict__ ws) {
    __shared__ int s[256];
    const int tid = threadIdx.x;
    int* cnt = (int*)ws + WS_CNT;
    int* off = (int*)ws + WS_OFF;
    int* cur = (int*)ws + WS_CUR;
    int i = blockIdx.x * 256 + tid;
    int v = (i < N_NODES) ? cnt[i] : 0;
    s[tid] = v;
    __syncthreads();
    #pragma unroll
    for (int d = 1; d < 256; d <<= 1) {
        int t = (tid >= d) ? s[tid - d] : 0;
        __syncthreads();
        s[tid] += t;
        __syncthreads();
    }
    int o = ((int*)ws + WS_CHS)[blockIdx.x] + s[tid] - v;
    if (i < N_NODES) { off[i] = o; cur[i] = o; }
}

// ---- scatter: sortedSrc[pos in dst segment] = src --------------------------
__global__ void k_scatter(const int* __restrict__ ei, float* __restrict__ ws) {
    int e = blockIdx.x * 256 + threadIdx.x;
    if (e >= N_EDGES) return;
    int d = ei[N_EDGES + e];
    int s = ei[e];
    int* cur = (int*)ws + WS_CUR;
    int pos = atomicAdd(&cur[d], 1);
    ((int*)ws + WS_SORT)[pos] = s;
}

// ---- gather: buf[r] = x[r] + sum_{e in seg(r)} x[src_e], wave per row ------
__global__ __launch_bounds__(256) void k_gather(const float* __restrict__ x,
                                                float* __restrict__ ws) {
    const int tid  = threadIdx.x;
    const int lane = tid & 63;
    const int wv   = tid >> 6;
    const int r = blockIdx.x * 4 + wv;
    if (r >= N_NODES) return;
    const int* off = (const int*)ws + WS_OFF;
    const int* ss  = (const int*)ws + WS_SORT;
    const int lo = off[r], hi = off[r + 1];
    float acc0 = x[(size_t)r * N_FEAT + lane];
    float acc1 = x[(size_t)r * N_FEAT + 64 + lane];
    int e = lo;
    for (; e + 4 <= hi; e += 4) {
        int s0 = ss[e], s1 = ss[e + 1], s2 = ss[e + 2], s3 = ss[e + 3];
        const float* p0 = x + (size_t)s0 * N_FEAT;
        const float* p1 = x + (size_t)s1 * N_FEAT;
        const float* p2 = x + (size_t)s2 * N_FEAT;
        const float* p3 = x + (size_t)s3 * N_FEAT;
        float a0 = p0[lane], b0 = p0[64 + lane];
        float a1 = p1[lane], b1 = p1[64 + lane];
        float a2 = p2[lane], b2 = p2[64 + lane];
        float a3 = p3[lane], b3 = p3[64 + lane];
        acc0 += a0 + a1 + a2 + a3;
        acc1 += b0 + b1 + b2 + b3;
    }
    for (; e < hi; ++e) {
        const float* p = x + (size_t)ss[e] * N_FEAT;
        acc0 += p[lane];
        acc1 += p[64 + lane];
    }
    float* buf = ws + WS_BUF;
    buf[(size_t)r * N_FEAT + lane]      = acc0;
    buf[(size_t)r * N_FEAT + 64 + lane] = acc1;
}

// ------------- fused nn1: x1 = relu(relu(h0@W1a+b1a)@W1b+b1b), in place ------
__global__ __launch_bounds__(256, 2) void k_mlp(float* __restrict__ buf,
        const float* __restrict__ W1a, const float* __restrict__ b1a,
        const float* __restrict__ W1b, const float* __restrict__ b1b) {
    __shared__ float As[64 * SR];
    __shared__ float Ts[64 * SR];
    const int tid = threadIdx.x;
    const int fg = tid & 15;      // 16 feat groups x 8 feats
    const int rg = tid >> 4;      // 16 row groups  x 4 rows
    const int row0 = blockIdx.x * 64;

    #pragma unroll
    for (int p = 0; p < 8; ++p) {
        int f4 = tid + p * 256;
        int r = f4 >> 5, c = (f4 & 31) * 4;
        float4 v = make_float4(0.f, 0.f, 0.f, 0.f);
        if (row0 + r < N_NODES) v = *(const float4*)(buf + (size_t)(row0 + r) * N_FEAT + c);
        *(float4*)(As + r * SR + c) = v;
    }
    __syncthreads();

    float acc[4][8];
    #pragma unroll
    for (int i = 0; i < 4; ++i)
        #pragma unroll
        for (int j = 0; j < 8; ++j) acc[i][j] = 0.f;

    #pragma unroll 4
    for (int k = 0; k < N_FEAT; ++k) {
        const float4 w0 = *(const float4*)(W1a + k * N_FEAT + fg * 8);
        const float4 w1 = *(const float4*)(W1a + k * N_FEAT + fg * 8 + 4);
        #pragma unroll
        for (int i = 0; i < 4; ++i) {
            const float a = As[(rg * 4 + i) * SR + k];
            acc[i][0] += a * w0.x; acc[i][1] += a * w0.y;
            acc[i][2] += a * w0.z; acc[i][3] += a * w0.w;
            acc[i][4] += a * w1.x; acc[i][5] += a * w1.y;
            acc[i][6] += a * w1.z; acc[i][7] += a * w1.w;
        }
    }
    {
        const float4 ba0 = *(const float4*)(b1a + fg * 8);
        const float4 ba1 = *(const float4*)(b1a + fg * 8 + 4);
        #pragma unroll
        for (int i = 0; i < 4; ++i) {
            float4 u0, u1;
            u0.x = fmaxf(acc[i][0] + ba0.x, 0.f); u0.y = fmaxf(acc[i][1] + ba0.y, 0.f);
            u0.z = fmaxf(acc[i][2] + ba0.z, 0.f); u0.w = fmaxf(acc[i][3] + ba0.w, 0.f);
            u1.x = fmaxf(acc[i][4] + ba1.x, 0.f); u1.y = fmaxf(acc[i][5] + ba1.y, 0.f);
            u1.z = fmaxf(acc[i][6] + ba1.z, 0.f); u1.w = fmaxf(acc[i][7] + ba1.w, 0.f);
            *(float4*)(Ts + (rg * 4 + i) * SR + fg * 8)     = u0;
            *(float4*)(Ts + (rg * 4 + i) * SR + fg * 8 + 4) = u1;
        }
    }
    __syncthreads();

    #pragma unroll
    for (int i = 0; i < 4; ++i)
        #pragma unroll
        for (int j = 0; j < 8; ++j) acc[i][j] = 0.f;

    #pragma unroll 4
    for (int k = 0; k < N_FEAT; ++k) {
        const float4 w0 = *(const float4*)(W1b + k * N_FEAT + fg * 8);
        const float4 w1 = *(const float4*)(W1b + k * N_FEAT + fg * 8 + 4);
        #pragma unroll
        for (int i = 0; i < 4; ++i) {
            const float a = Ts[(rg * 4 + i) * SR + k];
            acc[i][0] += a * w0.x; acc[i][1] += a * w0.y;
            acc[i][2] += a * w0.z; acc[i][3] += a * w0.w;
            acc[i][4] += a * w1.x; acc[i][5] += a * w1.y;
            acc[i][6] += a * w1.z; acc[i][7] += a * w1.w;
        }
    }
    {
        const float4 bb0 = *(const float4*)(b1b + fg * 8);
        const float4 bb1 = *(const float4*)(b1b + fg * 8 + 4);
        #pragma unroll
        for (int i = 0; i < 4; ++i) {
            int r = row0 + rg * 4 + i;
            if (r < N_NODES) {
                float4 u0, u1;
                u0.x = fmaxf(acc[i][0] + bb0.x, 0.f); u0.y = fmaxf(acc[i][1] + bb0.y, 0.f);
                u0.z = fmaxf(acc[i][2] + bb0.z, 0.f); u0.w = fmaxf(acc[i][3] + bb0.w, 0.f);
                u1.x = fmaxf(acc[i][4] + bb1.x, 0.f); u1.y = fmaxf(acc[i][5] + bb1.y, 0.f);
                u1.z = fmaxf(acc[i][6] + bb1.z, 0.f); u1.w = fmaxf(acc[i][7] + bb1.w, 0.f);
                *(float4*)(buf + (size_t)r * N_FEAT + fg * 8)     = u0;
                *(float4*)(buf + (size_t)r * N_FEAT + fg * 8 + 4) = u1;
            }
        }
    }
}

// --------- column sums / sums-of-squares of x1 (for BN batch stats) ---------
__global__ void k_stats(const float* __restrict__ buf, float* __restrict__ stats) {
    __shared__ float S[8][128];
    __shared__ float Q[8][128];
    const int tid = threadIdx.x;
    const int cg = tid & 31;
    const int rg = tid >> 5;
    float4 s = make_float4(0.f, 0.f, 0.f, 0.f);
    float4 q = make_float4(0.f, 0.f, 0.f, 0.f);
    for (int r = blockIdx.x * 8 + rg; r < N_NODES; r += gridDim.x * 8) {
        float4 v = *(const float4*)(buf + (size_t)r * N_FEAT + cg * 4);
        s.x += v.x; s.y += v.y; s.z += v.z; s.w += v.w;
        q.x += v.x * v.x; q.y += v.y * v.y; q.z += v.z * v.z; q.w += v.w * v.w;
    }
    S[rg][cg * 4 + 0] = s.x; S[rg][cg * 4 + 1] = s.y;
    S[rg][cg * 4 + 2] = s.z; S[rg][cg * 4 + 3] = s.w;
    Q[rg][cg * 4 + 0] = q.x; Q[rg][cg * 4 + 1] = q.y;
    Q[rg][cg * 4 + 2] = q.z; Q[rg][cg * 4 + 3] = q.w;
    __syncthreads();
    if (tid < 128) {
        float t = 0.f;
        #pragma unroll
        for (int g = 0; g < 8; ++g) t += S[g][tid];
        unsafeAtomicAdd(stats + tid, t);
    } else {
        int c = tid - 128;
        float t = 0.f;
        #pragma unroll
        for (int g = 0; g < 8; ++g) t += Q[g][c];
        unsafeAtomicAdd(stats + 128 + c, t);
    }
}

__global__ void k_finalize(const float* __restrict__ gamma, const float* __restrict__ beta,
                           float* __restrict__ ws) {
    int c = threadIdx.x;
    float mean = ws[WS_STATS + c] * (1.f / N_NODES);
    float var  = fmaxf(ws[WS_STATS + 128 + c] * (1.f / N_NODES) - mean * mean, 0.f);
    float sc = gamma[c] * rsqrtf(var + 1e-5f);
    ws[WS_SCALE + c] = sc;
    ws[WS_SCALE + 128 + c] = beta[c] - mean * sc;
}

__device__ __forceinline__ int lbound(const int* __restrict__ a, int n, int v) {
    int lo = 0, hi = n;
    while (lo < hi) { int m = (lo + hi) >> 1; if (a[m] < v) lo = m + 1; else hi = m; }
    return lo;
}

// --------- per-graph mean pool with BN applied on the fly -------------------
__global__ void k_pool(const float* __restrict__ buf, const int* __restrict__ batch,
                       float* __restrict__ ws) {
    __shared__ float S[8][128];
    __shared__ int range[2];
    const int g = blockIdx.x, tid = threadIdx.x;
    if (tid == 0) {
        range[0] = lbound(batch, N_NODES, g);
        range[1] = lbound(batch, N_NODES, g + 1);
    }
    __syncthreads();
    const int lo = range[0], hi = range[1];
    const int cg = tid & 31, rg = tid >> 5;
    float4 s = make_float4(0.f, 0.f, 0.f, 0.f);
    for (int r = lo + rg; r < hi; r += 8) {
        float4 v = *(const float4*)(buf + (size_t)r * N_FEAT + cg * 4);
        s.x += v.x; s.y += v.y; s.z += v.z; s.w += v.w;
    }
    S[rg][cg * 4 + 0] = s.x; S[rg][cg * 4 + 1] = s.y;
    S[rg][cg * 4 + 2] = s.z; S[rg][cg * 4 + 3] = s.w;
    __syncthreads();
    if (tid < 128) {
        float t = 0.f;
        #pragma unroll
        for (int g8 = 0; g8 < 8; ++g8) t += S[g8][tid];
        int cnt = hi - lo;
        float sc = ws[WS_SCALE + tid], sh = ws[WS_SCALE + 128 + tid];
        ws[WS_XG + g * N_FEAT + tid] = (cnt > 0) ? (sc * t / (float)cnt + sh) : 0.f;
    }
}

// --------- 10-iter gated recurrence + output MLP, block per graph -----------
__global__ __launch_bounds__(256) void k_recur(const float* __restrict__ ws,
        const float* __restrict__ Wl1, const float* __restrict__ bl1,
        const float* __restrict__ Wl2, const float* __restrict__ bl2,
        const float* __restrict__ Wm1, const float* __restrict__ bm1,
        const float* __restrict__ Wm2, const float* __restrict__ bm2,
        float* __restrict__ out) {
    __shared__ float W1h[128 * 64];
    __shared__ float W2h[128 * 64];
    __shared__ float xg_s[128];
    __shared__ float h_s[128];
    __shared__ float px[2][64];
    __shared__ float pq[2][2][64];
    __shared__ float m_s[DIMM];
    const int g = blockIdx.x, tid = threadIdx.x;

    for (int i = tid; i < 128 * 64; i += 256) {
        W1h[i] = Wl1[128 * 64 + i];
        W2h[i] = Wl2[128 * 64 + i];
    }
    if (tid < 128) {
        float v = ws[WS_XG + g * N_FEAT + tid];
        xg_s[tid] = v;
        h_s[tid] = v;
    }
    __syncthreads();

    const int sel  = tid >> 7;
    const int part = (tid >> 6) & 1;
    const int j    = tid & 63;

    {
        const float* Wg = sel ? Wl2 : Wl1;
        float a = 0.f;
        const int k0 = part * 64;
        #pragma unroll 4
        for (int k = 0; k < 64; ++k) a += xg_s[k0 + k] * Wg[(k0 + k) * 64 + j];
        pq[sel][part][j] = a;
    }
    __syncthreads();
    if (part == 0) {
        const float* bias = sel ? bl2 : bl1;
        px[sel][j] = pq[sel][0][j] + pq[sel][1][j] + bias[j];
    }
    __syncthreads();

    const float* Wh = sel ? W2h : W1h;
    for (int it = 0; it < N_ITERS; ++it) {
        float a = 0.f;
        const int k0 = part * 64;
        #pragma unroll
        for (int k = 0; k < 64; k += 4) {
            const float4 h4 = *(const float4*)(h_s + k0 + k);
            a += h4.x * Wh[(k0 + k + 0) * 64 + j];
            a += h4.y * Wh[(k0 + k + 1) * 64 + j];
            a += h4.z * Wh[(k0 + k + 2) * 64 + j];
            a += h4.w * Wh[(k0 + k + 3) * 64 + j];
        }
        pq[sel][part][j] = a;
        __syncthreads();
        if (part == 0) {
            float tot = pq[sel][0][j] + pq[sel][1][j] + px[sel][j];
            if (sel == 0) h_s[64 + j] = 1.f / (1.f + expf(-tot));
            else          h_s[j] = tanhf(tot);
        }
        __syncthreads();
    }

    if (tid < DIMM) {
        float a = bm1[tid];
        #pragma unroll 4
        for (int k = 0; k < 128; ++k) a += h_s[k] * Wm1[k * DIMM + tid];
        m_s[tid] = fmaxf(a, 0.f);
    }
    __syncthreads();
    if (tid < N_OUTD) {
        float a = bm2[tid];
        for (int k = 0; k < DIMM; ++k) a += m_s[k] * Wm2[k * N_OUTD + tid];
        out[g * N_OUTD + tid] = a;
    }
}

extern "C" void kernel_launch(void* const* d_in, const int* in_sizes, int n_in,
                              void* d_out, int out_size, void* d_ws, size_t ws_size,
                              hipStream_t stream) {
    const float* x     = (const float*)d_in[0];
    const int*   ei    = (const int*)d_in[1];
    const int*   batch = (const int*)d_in[2];
    const float* W1a = (const float*)d_in[3];
    const float* b1a = (const float*)d_in[4];
    const float* W1b = (const float*)d_in[5];
    const float* b1b = (const float*)d_in[6];
    const float* gamma = (const float*)d_in[7];
    const float* beta  = (const float*)d_in[8];
    const float* Wl1 = (const float*)d_in[9];
    const float* bl1 = (const float*)d_in[10];
    const float* Wl2 = (const float*)d_in[11];
    const float* bl2 = (const float*)d_in[12];
    const float* Wm1 = (const float*)d_in[13];
    const float* bm1 = (const float*)d_in[14];
    const float* Wm2 = (const float*)d_in[15];
    const float* bm2 = (const float*)d_in[16];
    float* out = (float*)d_out;
    float* ws  = (float*)d_ws;

    k_zero   <<<(N_NODES + 255) / 256, 256, 0, stream>>>(ws);
    k_hist   <<<(N_EDGES + 255) / 256, 256, 0, stream>>>(ei, ws);
    k_chunk  <<<N_CHUNKS, 256, 0, stream>>>(ws);
    k_scan0  <<<1, 256, 0, stream>>>(ws);
    k_scan1  <<<N_CHUNKS, 256, 0, stream>>>(ws);
    k_scatter<<<(N_EDGES + 255) / 256, 256, 0, stream>>>(ei, ws);
    k_gather <<<(N_NODES + 3) / 4, 256, 0, stream>>>(x, ws);
    k_mlp    <<<(N_NODES + 63) / 64, 256, 0, stream>>>(ws + WS_BUF, W1a, b1a, W1b, b1b);
    k_stats  <<<512, 256, 0, stream>>>(ws + WS_BUF, ws + WS_STATS);
    k_finalize<<<1, 128, 0, stream>>>(gamma, beta, ws);
    k_pool   <<<N_GRAPHS, 256, 0, stream>>>(ws + WS_BUF, batch, ws);
    k_recur  <<<N_GRAPHS, 256, 0, stream>>>(ws, Wl1, bl1, Wl2, bl2, Wm1, bm1, Wm2, bm2, out);
}